// Round 13
// baseline (138.852 us; speedup 1.0000x reference)
//
#include <hip/hip_runtime.h>
#include <math.h>

#define BB 16
#define TT 4096
#define CC 128

// R22: two independent streams per wave (fwd + bwd of the SAME chunk).
// R17/R18 lessons: same-block waves are barrier-lockstep (no stall overlap);
// extra blocks/CU pay warmup amplification. Fix: ILP inside the wave --
// each block owns chunk c's fwd AND bwd streams; their serial chains
// (ds_read->MFMA->mul->pkbf->ds_write) are independent and share the ONE
// barrier, so one stream's stall is filled by the other's issue.
// LCH=16 -> NCH=256 -> grid = 256 blocks = 1/CU, 8 waves.
// NS = 27 FIXED for all blocks: edge chunks run guarded extra steps
// (loads clamped to [0, TT-1]; stores double-guarded wlo<=row<whi; exact
// seeds for row 0 / row TT-1 preserved). Work/CU 43->54 stream-steps, but
// paired-step wall << 2x single (chains overlap).
#define LCH 16
#define WCH 12
#define NCH (TT / LCH)   // 256
#define NSS (LCH - 1 + WCH)  // 27

#define ECS 136          // E row stride in bf16 units (272 B, 16B-aligned)

typedef float    f32x4  __attribute__((ext_vector_type(4)));
typedef unsigned uint4v __attribute__((ext_vector_type(4)));
typedef __bf16   bf16x8 __attribute__((ext_vector_type(8)));

// ---------------------------------------------------------------------------
// ws layout:
//   [0, 131072 B)                      B-fragments: [dir][T][kc][h][lane][8] bf16
//   [131072 B, +BB*TT*CC*4)            beta
// ---------------------------------------------------------------------------

__device__ __forceinline__ float wave_reduce_max(float v) {
#pragma unroll
    for (int o = 1; o < 64; o <<= 1) v = fmaxf(v, __shfl_xor(v, o, 64));
    return v;
}
__device__ __forceinline__ float wave_reduce_sum(float v) {
#pragma unroll
    for (int o = 1; o < 64; o <<= 1) v += __shfl_xor(v, o, 64);
    return v;
}

// LDS-only barrier: skip the conservative vmcnt(0) drain so global
// prefetch/stores stay in flight across the barrier.
__device__ __forceinline__ void lds_barrier() {
    __asm__ __volatile__("s_waitcnt lgkmcnt(0)" ::: "memory");
    __builtin_amdgcn_s_barrier();
}

// Truncation hi/lo bf16 split, packed hi|lo<<16. hi = top16(f) (trunc);
// lo = f - hi is EXACT in f32.
__device__ __forceinline__ unsigned pkbf(float f) {
    unsigned u = __float_as_uint(f);
    float hi = __uint_as_float(u & 0xffff0000u);
    float lo = f - hi;
    return (u >> 16) | (__float_as_uint(lo) & 0xffff0000u);
}

// ---------------------------------------------------------------------------
// Prep: P = exp(log_softmax(log_trans, axis=1)); emit MFMA B-fragments for
// both directions, hi/lo split. (Identical to R16-R21.)
//   fwd (dir 0): B[k][n] = P[k][n]   bwd (dir 1): B[k][n] = P[n][k]
// Fragment of B element (k, n): T=n>>4, kc=k>>5, lane=(((k&31)>>3)<<4)|(n&15),
// e=k&7; slot ((((dir*8+T)*4+kc)*2+h)*64+lane)*8+e.
// ---------------------------------------------------------------------------
__global__ __launch_bounds__(CC) void prep_kernel(const float* __restrict__ lt,
                                                  unsigned short* __restrict__ fr) {
    const int r  = blockIdx.x;
    const int j  = threadIdx.x;
    const int wv = j >> 6;
    __shared__ float sm[2];

    float x = lt[r * CC + j];
    float m = wave_reduce_max(x);
    if ((j & 63) == 0) sm[wv] = m;
    __syncthreads();
    m = fmaxf(sm[0], sm[1]);
    __syncthreads();
    float e = __expf(x - m);
    float s = wave_reduce_sum(e);
    if ((j & 63) == 0) sm[wv] = s;
    __syncthreads();
    s = sm[0] + sm[1];
    float p = e / s;

    unsigned pk = pkbf(p);
    unsigned short phi = (unsigned short)(pk & 0xffffu);
    unsigned short plo = (unsigned short)(pk >> 16);

    {   // dir 0 (fwd): k = r, n = j
        int T = j >> 4, col = j & 15, kc = r >> 5;
        int ln = (((r & 31) >> 3) << 4) | col, e8 = r & 7;
        size_t o = ((((size_t)(0 * 8 + T) * 4 + kc) * 2 + 0) * 64 + ln) * 8 + e8;
        fr[o] = phi; fr[o + 512] = plo;
    }
    {   // dir 1 (bwd): k = j, n = r
        int T = r >> 4, col = r & 15, kc = j >> 5;
        int ln = (((j & 31) >> 3) << 4) | col, e8 = j & 7;
        size_t o = ((((size_t)(1 * 8 + T) * 4 + kc) * 2 + 0) * 64 + ln) * 8 + e8;
        fr[o] = phi; fr[o + 512] = plo;
    }
}

// ---- B fragments per stream S in {F,B}: tile T = wv, 4 kc x {hi,lo} ----
#define BDECL(S)                                                               \
    bf16x8 Bh##S##_0, Bh##S##_1, Bh##S##_2, Bh##S##_3,                         \
           Bl##S##_0, Bl##S##_1, Bl##S##_2, Bl##S##_3

#define BLOAD(S, DIR, kc)                                                      \
    do {                                                                       \
        size_t o = ((((size_t)((DIR) * 8 + wv) * 4 + (kc)) * 2)                \
                        * 64 + lane) * 8;                                      \
        Bh##S##_##kc = __builtin_bit_cast(bf16x8, *(const uint4v*)(fr + o));   \
        Bl##S##_##kc =                                                         \
            __builtin_bit_cast(bf16x8, *(const uint4v*)(fr + o + 512));        \
    } while (0)

// One K-chunk for stream S: 2 direct b128 A-frag reads, 3 MFMAs into the
// stream's accumulators. A-frag k-map = (lane>>4)*8+e -- same map as B
// (prep), so any true-HW k-permutation cancels.
#define KC_STEP(S, kc)                                                         \
    do {                                                                       \
        bf16x8 Ah = __builtin_bit_cast(                                        \
            bf16x8, *(const uint4v*)(ehp##S + arow + (kc) * 32));              \
        bf16x8 Al = __builtin_bit_cast(                                        \
            bf16x8, *(const uint4v*)(elp##S + arow + (kc) * 32));              \
        aHH##S = __builtin_amdgcn_mfma_f32_16x16x32_bf16(Ah, Bh##S##_##kc, aHH##S, 0, 0, 0); \
        aHL##S = __builtin_amdgcn_mfma_f32_16x16x32_bf16(Ah, Bl##S##_##kc, aHL##S, 0, 0, 0); \
        aLH##S = __builtin_amdgcn_mfma_f32_16x16x32_bf16(Al, Bh##S##_##kc, aLH##S, 0, 0, 0); \
    } while (0)

#define LOADU(d0, RO)                                                          \
    do {                                                                       \
        d0.x = ub0[(RO) + n1]; d0.y = ub1[(RO) + n1];                          \
        d0.z = ub2[(RO) + n1]; d0.w = ub3[(RO) + n1];                          \
    } while (0)

// col-0 broadcast loads (the u-only scale increments)
#define LOADW(d0, RO)                                                          \
    do {                                                                       \
        d0.x = ub0[(RO)]; d0.y = ub1[(RO)];                                    \
        d0.z = ub2[(RO)]; d0.w = ub3[(RO)];                                    \
    } while (0)

#define STOREO(S, s0, RO)                                                      \
    do {                                                                       \
        ob##S##0[(RO) + n1] = s0.x; ob##S##1[(RO) + n1] = s0.y;                \
        ob##S##2[(RO) + n1] = s0.z; ob##S##3[(RO) + n1] = s0.w;                \
    } while (0)

#define EPUB(dst_h, dst_l, I, V)                                               \
    do {                                                                       \
        unsigned pk_ = pkbf(V);                                                \
        dst_h[(bb + I) * ECS + n1] = (unsigned short)pk_;                      \
        dst_l[(bb + I) * ECS + n1] = (unsigned short)(pk_ >> 16);              \
    } while (0)

// ---------------------------------------------------------------------------
// Paired-stream chunked scan, MFMA contraction, ONE barrier per step.
// Grid = NCH = 256 blocks (1/CU) of 512 threads (8 waves). Block c runs the
// fwd (alpha) AND bwd (beta) streams of chunk c concurrently (per-wave ILP).
// Wave wv owns n-tile wv for both streams; lane holds chains b =
// (lane>>4)*4+reg, col n1 = 16wv + (lane&15) (MFMA C/D layout, m89-verified).
// u-only scale (R20): f = exp(uc - dc), E_next = acc * f, st = log(acc)
// (+uc for fwd). NS=27 fixed; loads clamped, stores guarded to the window.
// ---------------------------------------------------------------------------
__global__ __launch_bounds__(512, 1)
void scan_kernel(const float* __restrict__ u,
                 const unsigned short* __restrict__ fr,
                 float* __restrict__ alpha,
                 float* __restrict__ beta) {
    const int t    = threadIdx.x;     // 0..511
    const int lane = t & 63;
    const int wv   = t >> 6;          // wave -> n-tile wv
    const int col  = lane & 15;
    const int bb   = (lane >> 4) * 4; // first of this lane's 4 chains
    const int n1   = wv * 16 + col;

    const int c = blockIdx.x;         // chunk id

    __shared__ alignas(16) unsigned short EhF[2][16 * ECS];
    __shared__ alignas(16) unsigned short ElF[2][16 * ECS];
    __shared__ alignas(16) unsigned short EhB[2][16 * ECS];
    __shared__ alignas(16) unsigned short ElB[2][16 * ECS];

    // B fragments (MFMA can source VGPR or AGPR; AGPR parking is harmless).
    BDECL(F); BDECL(B);
    BLOAD(F, 0, 0); BLOAD(F, 0, 1); BLOAD(F, 0, 2); BLOAD(F, 0, 3);
    BLOAD(B, 1, 0); BLOAD(B, 1, 1); BLOAD(B, 1, 2); BLOAD(B, 1, 3);

    const float* ub0 = u + (size_t)(bb + 0) * TT * CC;
    const float* ub1 = u + (size_t)(bb + 1) * TT * CC;
    const float* ub2 = u + (size_t)(bb + 2) * TT * CC;
    const float* ub3 = u + (size_t)(bb + 3) * TT * CC;
    float* obF0 = alpha + (size_t)(bb + 0) * TT * CC;
    float* obF1 = alpha + (size_t)(bb + 1) * TT * CC;
    float* obF2 = alpha + (size_t)(bb + 2) * TT * CC;
    float* obF3 = alpha + (size_t)(bb + 3) * TT * CC;
    float* obB0 = beta + (size_t)(bb + 0) * TT * CC;
    float* obB1 = beta + (size_t)(bb + 1) * TT * CC;
    float* obB2 = beta + (size_t)(bb + 2) * TT * CC;
    float* obB3 = beta + (size_t)(bb + 3) * TT * CC;

    const int wlo = c * LCH;
    const int whi = wlo + LCH;
    int t0 = wlo - WCH; if (t0 < 0) t0 = 0;
    int t1 = whi - 1 + WCH; if (t1 > TT - 1) t1 = TT - 1;

    const int roLim  = (TT - 1) * CC;
    const int wloOff = wlo * CC;
    const int whiOff = whi * CC;

    int roF = t0 * CC;
    int roB = t1 * CC;

    // Seeds: xF = u[t0] (exact alpha when t0==0); xB = u[t1] (beta=0 fold).
    float4 xF, dF, xB, dB;
    LOADU(xF, roF); LOADW(dF, roF);
    LOADU(xB, roB); LOADW(dB, roB);
    if (t0 == 0 && wlo == 0) STOREO(F, xF, 0);   // alpha row 0 = u[0], exact
    if (t1 == whi - 1) {
        float4 z4{0.f, 0.f, 0.f, 0.f};
        STOREO(B, z4, roB);                      // beta row TT-1 = 0, exact
    }
    {
        unsigned short* ehF0 = &EhF[0][0]; unsigned short* elF0 = &ElF[0][0];
        unsigned short* ehB0 = &EhB[0][0]; unsigned short* elB0 = &ElB[0][0];
        EPUB(ehF0, elF0, 0, __expf(xF.x - dF.x));
        EPUB(ehF0, elF0, 1, __expf(xF.y - dF.y));
        EPUB(ehF0, elF0, 2, __expf(xF.z - dF.z));
        EPUB(ehF0, elF0, 3, __expf(xF.w - dF.w));
        EPUB(ehB0, elB0, 0, __expf(xB.x - dB.x));
        EPUB(ehB0, elB0, 1, __expf(xB.y - dB.y));
        EPUB(ehB0, elB0, 2, __expf(xB.z - dB.z));
        EPUB(ehB0, elB0, 3, __expf(xB.w - dB.w));
    }

    // prefetch row r(1) per stream (in-range by construction)
    int rpfF = roF + CC, rpfB = roB - CC;
    float4 unF, dnF, unB, dnB;
    LOADU(unF, rpfF); LOADW(dnF, rpfF);
    LOADU(unB, rpfB); LOADW(dnB, rpfB);

    const int arow = (lane & 15) * ECS + (lane >> 4) * 8;  // A-frag base (u16)

    for (int s = 0; s < NSS; ++s) {
        const int par = s & 1;

        // ---- phase 1: slide both u pipelines; prefetch r(s+2) (clamped) ----
        float4 ucF = unF, dcF = dnF, ucB = unB, dcB = dnB;
        roF += CC; roB -= CC;
        rpfF += CC; rpfB -= CC;
        int rcF = rpfF > roLim ? roLim : rpfF;
        int rcB = rpfB < 0 ? 0 : rpfB;
        LOADU(unF, rcF); LOADW(dnF, rcF);
        LOADU(unB, rcB); LOADW(dnB, rcB);

        lds_barrier();  // E[par] of both streams published (the ONLY barrier)

        // ---- phase 2 ----
        // f = exp(uc - dc): pure input data -> overlaps the MFMAs
        float4 fF, fB;
        fF.x = __expf(ucF.x - dcF.x); fF.y = __expf(ucF.y - dcF.y);
        fF.z = __expf(ucF.z - dcF.z); fF.w = __expf(ucF.w - dcF.w);
        fB.x = __expf(ucB.x - dcB.x); fB.y = __expf(ucB.y - dcB.y);
        fB.z = __expf(ucB.z - dcB.z); fB.w = __expf(ucB.w - dcB.w);

        const unsigned short* ehpF = &EhF[par][0];
        const unsigned short* elpF = &ElF[par][0];
        const unsigned short* ehpB = &EhB[par][0];
        const unsigned short* elpB = &ElB[par][0];
        f32x4 aHHF = {0.f, 0.f, 0.f, 0.f}, aHLF = {0.f, 0.f, 0.f, 0.f},
              aLHF = {0.f, 0.f, 0.f, 0.f};
        f32x4 aHHB = {0.f, 0.f, 0.f, 0.f}, aHLB = {0.f, 0.f, 0.f, 0.f},
              aLHB = {0.f, 0.f, 0.f, 0.f};
        KC_STEP(F, 0); KC_STEP(B, 0);
        KC_STEP(F, 1); KC_STEP(B, 1);
        KC_STEP(F, 2); KC_STEP(B, 2);
        KC_STEP(F, 3); KC_STEP(B, 3);
        f32x4 accF = (aHHF + aHLF) + aLHF;
        f32x4 accB = (aHHB + aHLB) + aLHB;

        // E_next = acc * f: split hi/lo -> E[par^1] (readers one barrier away)
        unsigned short* ehnF = &EhF[par ^ 1][0];
        unsigned short* elnF = &ElF[par ^ 1][0];
        unsigned short* ehnB = &EhB[par ^ 1][0];
        unsigned short* elnB = &ElB[par ^ 1][0];
        EPUB(ehnF, elnF, 0, accF.x * fF.x);
        EPUB(ehnF, elnF, 1, accF.y * fF.y);
        EPUB(ehnF, elnF, 2, accF.z * fF.z);
        EPUB(ehnF, elnF, 3, accF.w * fF.w);
        EPUB(ehnB, elnB, 0, accB.x * fB.x);
        EPUB(ehnB, elnB, 1, accB.y * fB.y);
        EPUB(ehnB, elnB, 2, accB.z * fB.z);
        EPUB(ehnB, elnB, 3, accB.w * fB.w);

        // outputs (off the serial chain); per-row constant -W dropped
        float4 stF, stB;
        stF.x = __logf(accF.x) + ucF.x;
        stF.y = __logf(accF.y) + ucF.y;
        stF.z = __logf(accF.z) + ucF.z;
        stF.w = __logf(accF.w) + ucF.w;
        if (roF >= wloOff && roF < whiOff) STOREO(F, stF, roF);
        stB.x = __logf(accB.x);
        stB.y = __logf(accB.y);
        stB.z = __logf(accB.z);
        stB.w = __logf(accB.w);
        if (roB >= wloOff && roB < whiOff) STOREO(B, stB, roB);
    }
}

// ---------------------------------------------------------------------------
// Combine: out = log_softmax(alpha + beta, axis=-1), in place over d_out.
// float4 per lane; each 32-lane half-wave owns one row (128 floats).
// ---------------------------------------------------------------------------
__global__ __launch_bounds__(256) void combine_kernel(float* __restrict__ out,
                                                      const float* __restrict__ beta) {
    const int    lane = threadIdx.x & 63;
    const int    li   = lane & 31;
    const size_t row  = (size_t)blockIdx.x * 8 + ((threadIdx.x >> 6) << 1) + (lane >> 5);

    float4*       o4 = (float4*)(out + row * CC);
    const float4* b4 = (const float4*)(beta + row * CC);

    float4 a = o4[li];
    float4 bb = b4[li];
    float4 z = float4{a.x + bb.x, a.y + bb.y, a.z + bb.z, a.w + bb.w};

    float m = fmaxf(fmaxf(z.x, z.y), fmaxf(z.z, z.w));
#pragma unroll
    for (int o = 1; o < 32; o <<= 1) m = fmaxf(m, __shfl_xor(m, o, 64));
    float s = __expf(z.x - m) + __expf(z.y - m) + __expf(z.z - m) + __expf(z.w - m);
#pragma unroll
    for (int o = 1; o < 32; o <<= 1) s += __shfl_xor(s, o, 64);
    float ls = m + __logf(s);
    o4[li] = float4{z.x - ls, z.y - ls, z.z - ls, z.w - ls};
}

// ---------------------------------------------------------------------------
extern "C" void kernel_launch(void* const* d_in, const int* in_sizes, int n_in,
                              void* d_out, int out_size, void* d_ws, size_t ws_size,
                              hipStream_t stream) {
    const float* u_in = (const float*)d_in[0];   // (B, T, C) fp32
    const float* lt   = (const float*)d_in[1];   // (C, C)    fp32
    float*       out  = (float*)d_out;           // (B, T, C) fp32

    unsigned short* fr = (unsigned short*)d_ws;          // 131072 B of B-frags
    float* beta = (float*)d_ws + 2 * CC * CC;            // same offset as before

    prep_kernel<<<CC, CC, 0, stream>>>(lt, fr);
    scan_kernel<<<NCH, 512, 0, stream>>>(u_in, fr, out, beta);
    combine_kernel<<<(BB * TT) / 8, 256, 0, stream>>>(out, beta);
}

// Round 14
// 131.800 us; speedup vs baseline: 1.0535x; 1.0535x over previous
//
#include <hip/hip_runtime.h>
#include <math.h>

#define BB 16
#define TT 4096
#define CC 128

// R23: fused combine tail + WCH=8 on the R22 paired-stream kernel.
// R22 post-mortem: paired-step 4840 cyc -> per-stream 2420 (ILP overlap
// real, -13% vs R21) but +26% stream-steps ate it. Keep the pairing for a
// STRUCTURAL win it enables: block c computes BOTH alpha and beta for the
// SAME window rows, so a fused tail can finalize out = log_softmax(a+b)
// for its own window from L2-hot just-written rows (one __syncthreads
// with vmcnt drain orders block-own stores before reads; same CU -> same
// L1/L2 path). The separate combine kernel (67MB HBM re-read + launch) is
// deleted. Also WCH 12->8: contraction ~0.12/step (absmax bit-identical
// W=512..12); residual 4e-8 rel (2.2e-4 at 3x-pessimistic 0.35/step),
// 280x under the 0.0625 floor. NSS 27->23.
#define LCH 16
#define WCH 8
#define NCH (TT / LCH)   // 256
#define NSS (LCH - 1 + WCH)  // 23

#define ECS 136          // E row stride in bf16 units (272 B, 16B-aligned)

typedef float    f32x4  __attribute__((ext_vector_type(4)));
typedef unsigned uint4v __attribute__((ext_vector_type(4)));
typedef __bf16   bf16x8 __attribute__((ext_vector_type(8)));

// ---------------------------------------------------------------------------
// ws layout:
//   [0, 131072 B)                      B-fragments: [dir][T][kc][h][lane][8] bf16
//   [131072 B, +BB*TT*CC*4)            beta
// ---------------------------------------------------------------------------

__device__ __forceinline__ float wave_reduce_max(float v) {
#pragma unroll
    for (int o = 1; o < 64; o <<= 1) v = fmaxf(v, __shfl_xor(v, o, 64));
    return v;
}
__device__ __forceinline__ float wave_reduce_sum(float v) {
#pragma unroll
    for (int o = 1; o < 64; o <<= 1) v += __shfl_xor(v, o, 64);
    return v;
}

// LDS-only barrier: skip the conservative vmcnt(0) drain so global
// prefetch/stores stay in flight across the barrier.
__device__ __forceinline__ void lds_barrier() {
    __asm__ __volatile__("s_waitcnt lgkmcnt(0)" ::: "memory");
    __builtin_amdgcn_s_barrier();
}

// Truncation hi/lo bf16 split, packed hi|lo<<16. hi = top16(f) (trunc);
// lo = f - hi is EXACT in f32.
__device__ __forceinline__ unsigned pkbf(float f) {
    unsigned u = __float_as_uint(f);
    float hi = __uint_as_float(u & 0xffff0000u);
    float lo = f - hi;
    return (u >> 16) | (__float_as_uint(lo) & 0xffff0000u);
}

// ---------------------------------------------------------------------------
// Prep: P = exp(log_softmax(log_trans, axis=1)); emit MFMA B-fragments for
// both directions, hi/lo split. (Identical to R16-R22.)
//   fwd (dir 0): B[k][n] = P[k][n]   bwd (dir 1): B[k][n] = P[n][k]
// Fragment of B element (k, n): T=n>>4, kc=k>>5, lane=(((k&31)>>3)<<4)|(n&15),
// e=k&7; slot ((((dir*8+T)*4+kc)*2+h)*64+lane)*8+e.
// ---------------------------------------------------------------------------
__global__ __launch_bounds__(CC) void prep_kernel(const float* __restrict__ lt,
                                                  unsigned short* __restrict__ fr) {
    const int r  = blockIdx.x;
    const int j  = threadIdx.x;
    const int wv = j >> 6;
    __shared__ float sm[2];

    float x = lt[r * CC + j];
    float m = wave_reduce_max(x);
    if ((j & 63) == 0) sm[wv] = m;
    __syncthreads();
    m = fmaxf(sm[0], sm[1]);
    __syncthreads();
    float e = __expf(x - m);
    float s = wave_reduce_sum(e);
    if ((j & 63) == 0) sm[wv] = s;
    __syncthreads();
    s = sm[0] + sm[1];
    float p = e / s;

    unsigned pk = pkbf(p);
    unsigned short phi = (unsigned short)(pk & 0xffffu);
    unsigned short plo = (unsigned short)(pk >> 16);

    {   // dir 0 (fwd): k = r, n = j
        int T = j >> 4, col = j & 15, kc = r >> 5;
        int ln = (((r & 31) >> 3) << 4) | col, e8 = r & 7;
        size_t o = ((((size_t)(0 * 8 + T) * 4 + kc) * 2 + 0) * 64 + ln) * 8 + e8;
        fr[o] = phi; fr[o + 512] = plo;
    }
    {   // dir 1 (bwd): k = j, n = r
        int T = r >> 4, col = r & 15, kc = j >> 5;
        int ln = (((j & 31) >> 3) << 4) | col, e8 = j & 7;
        size_t o = ((((size_t)(1 * 8 + T) * 4 + kc) * 2 + 0) * 64 + ln) * 8 + e8;
        fr[o] = phi; fr[o + 512] = plo;
    }
}

// ---- B fragments per stream S in {F,B}: tile T = wv, 4 kc x {hi,lo} ----
#define BDECL(S)                                                               \
    bf16x8 Bh##S##_0, Bh##S##_1, Bh##S##_2, Bh##S##_3,                         \
           Bl##S##_0, Bl##S##_1, Bl##S##_2, Bl##S##_3

#define BLOAD(S, DIR, kc)                                                      \
    do {                                                                       \
        size_t o = ((((size_t)((DIR) * 8 + wv) * 4 + (kc)) * 2)                \
                        * 64 + lane) * 8;                                      \
        Bh##S##_##kc = __builtin_bit_cast(bf16x8, *(const uint4v*)(fr + o));   \
        Bl##S##_##kc =                                                         \
            __builtin_bit_cast(bf16x8, *(const uint4v*)(fr + o + 512));        \
    } while (0)

// One K-chunk for stream S: 2 direct b128 A-frag reads, 3 MFMAs into the
// stream's accumulators. A-frag k-map = (lane>>4)*8+e -- same map as B
// (prep), so any true-HW k-permutation cancels.
#define KC_STEP(S, kc)                                                         \
    do {                                                                       \
        bf16x8 Ah = __builtin_bit_cast(                                        \
            bf16x8, *(const uint4v*)(ehp##S + arow + (kc) * 32));              \
        bf16x8 Al = __builtin_bit_cast(                                        \
            bf16x8, *(const uint4v*)(elp##S + arow + (kc) * 32));              \
        aHH##S = __builtin_amdgcn_mfma_f32_16x16x32_bf16(Ah, Bh##S##_##kc, aHH##S, 0, 0, 0); \
        aHL##S = __builtin_amdgcn_mfma_f32_16x16x32_bf16(Ah, Bl##S##_##kc, aHL##S, 0, 0, 0); \
        aLH##S = __builtin_amdgcn_mfma_f32_16x16x32_bf16(Al, Bh##S##_##kc, aLH##S, 0, 0, 0); \
    } while (0)

#define LOADU(d0, RO)                                                          \
    do {                                                                       \
        d0.x = ub0[(RO) + n1]; d0.y = ub1[(RO) + n1];                          \
        d0.z = ub2[(RO) + n1]; d0.w = ub3[(RO) + n1];                          \
    } while (0)

// col-0 broadcast loads (the u-only scale increments)
#define LOADW(d0, RO)                                                          \
    do {                                                                       \
        d0.x = ub0[(RO)]; d0.y = ub1[(RO)];                                    \
        d0.z = ub2[(RO)]; d0.w = ub3[(RO)];                                    \
    } while (0)

#define STOREO(S, s0, RO)                                                      \
    do {                                                                       \
        ob##S##0[(RO) + n1] = s0.x; ob##S##1[(RO) + n1] = s0.y;                \
        ob##S##2[(RO) + n1] = s0.z; ob##S##3[(RO) + n1] = s0.w;                \
    } while (0)

#define EPUB(dst_h, dst_l, I, V)                                               \
    do {                                                                       \
        unsigned pk_ = pkbf(V);                                                \
        dst_h[(bb + I) * ECS + n1] = (unsigned short)pk_;                      \
        dst_l[(bb + I) * ECS + n1] = (unsigned short)(pk_ >> 16);              \
    } while (0)

// ---------------------------------------------------------------------------
// Paired-stream chunked scan + fused combine, ONE barrier per step.
// Grid = NCH = 256 blocks (1/CU) of 512 threads (8 waves). Block c runs the
// fwd (alpha) AND bwd (beta) streams of chunk c concurrently (per-wave ILP),
// then finalizes out = log_softmax(alpha+beta) for its own window rows
// (L2-hot: this block just wrote them).
// Wave wv owns n-tile wv for both streams; lane holds chains b =
// (lane>>4)*4+reg, col n1 = 16wv + (lane&15) (MFMA C/D layout, m89-verified).
// u-only scale (R20): f = exp(uc - dc), E_next = acc * f, st = log(acc)
// (+uc for fwd). NS=23 fixed; loads clamped, stores guarded to the window.
// ---------------------------------------------------------------------------
__global__ __launch_bounds__(512, 1)
void scan_kernel(const float* __restrict__ u,
                 const unsigned short* __restrict__ fr,
                 float* __restrict__ alpha,
                 float* __restrict__ beta) {
    const int t    = threadIdx.x;     // 0..511
    const int lane = t & 63;
    const int wv   = t >> 6;          // wave -> n-tile wv
    const int col  = lane & 15;
    const int bb   = (lane >> 4) * 4; // first of this lane's 4 chains
    const int n1   = wv * 16 + col;

    const int c = blockIdx.x;         // chunk id

    __shared__ alignas(16) unsigned short EhF[2][16 * ECS];
    __shared__ alignas(16) unsigned short ElF[2][16 * ECS];
    __shared__ alignas(16) unsigned short EhB[2][16 * ECS];
    __shared__ alignas(16) unsigned short ElB[2][16 * ECS];

    // B fragments (MFMA can source VGPR or AGPR; AGPR parking is harmless).
    BDECL(F); BDECL(B);
    BLOAD(F, 0, 0); BLOAD(F, 0, 1); BLOAD(F, 0, 2); BLOAD(F, 0, 3);
    BLOAD(B, 1, 0); BLOAD(B, 1, 1); BLOAD(B, 1, 2); BLOAD(B, 1, 3);

    const float* ub0 = u + (size_t)(bb + 0) * TT * CC;
    const float* ub1 = u + (size_t)(bb + 1) * TT * CC;
    const float* ub2 = u + (size_t)(bb + 2) * TT * CC;
    const float* ub3 = u + (size_t)(bb + 3) * TT * CC;
    float* obF0 = alpha + (size_t)(bb + 0) * TT * CC;
    float* obF1 = alpha + (size_t)(bb + 1) * TT * CC;
    float* obF2 = alpha + (size_t)(bb + 2) * TT * CC;
    float* obF3 = alpha + (size_t)(bb + 3) * TT * CC;
    float* obB0 = beta + (size_t)(bb + 0) * TT * CC;
    float* obB1 = beta + (size_t)(bb + 1) * TT * CC;
    float* obB2 = beta + (size_t)(bb + 2) * TT * CC;
    float* obB3 = beta + (size_t)(bb + 3) * TT * CC;

    const int wlo = c * LCH;
    const int whi = wlo + LCH;
    int t0 = wlo - WCH; if (t0 < 0) t0 = 0;
    int t1 = whi - 1 + WCH; if (t1 > TT - 1) t1 = TT - 1;

    const int roLim  = (TT - 1) * CC;
    const int wloOff = wlo * CC;
    const int whiOff = whi * CC;

    int roF = t0 * CC;
    int roB = t1 * CC;

    // Seeds: xF = u[t0] (exact alpha when t0==0); xB = u[t1] (beta=0 fold).
    float4 xF, dF, xB, dB;
    LOADU(xF, roF); LOADW(dF, roF);
    LOADU(xB, roB); LOADW(dB, roB);
    if (t0 == 0 && wlo == 0) STOREO(F, xF, 0);   // alpha row 0 = u[0], exact
    if (t1 == whi - 1) {
        float4 z4{0.f, 0.f, 0.f, 0.f};
        STOREO(B, z4, roB);                      // beta row TT-1 = 0, exact
    }
    {
        unsigned short* ehF0 = &EhF[0][0]; unsigned short* elF0 = &ElF[0][0];
        unsigned short* ehB0 = &EhB[0][0]; unsigned short* elB0 = &ElB[0][0];
        EPUB(ehF0, elF0, 0, __expf(xF.x - dF.x));
        EPUB(ehF0, elF0, 1, __expf(xF.y - dF.y));
        EPUB(ehF0, elF0, 2, __expf(xF.z - dF.z));
        EPUB(ehF0, elF0, 3, __expf(xF.w - dF.w));
        EPUB(ehB0, elB0, 0, __expf(xB.x - dB.x));
        EPUB(ehB0, elB0, 1, __expf(xB.y - dB.y));
        EPUB(ehB0, elB0, 2, __expf(xB.z - dB.z));
        EPUB(ehB0, elB0, 3, __expf(xB.w - dB.w));
    }

    // prefetch row r(1) per stream (in-range by construction)
    int rpfF = roF + CC, rpfB = roB - CC;
    float4 unF, dnF, unB, dnB;
    LOADU(unF, rpfF); LOADW(dnF, rpfF);
    LOADU(unB, rpfB); LOADW(dnB, rpfB);

    const int arow = (lane & 15) * ECS + (lane >> 4) * 8;  // A-frag base (u16)

    for (int s = 0; s < NSS; ++s) {
        const int par = s & 1;

        // ---- phase 1: slide both u pipelines; prefetch r(s+2) (clamped) ----
        float4 ucF = unF, dcF = dnF, ucB = unB, dcB = dnB;
        roF += CC; roB -= CC;
        rpfF += CC; rpfB -= CC;
        int rcF = rpfF > roLim ? roLim : rpfF;
        int rcB = rpfB < 0 ? 0 : rpfB;
        LOADU(unF, rcF); LOADW(dnF, rcF);
        LOADU(unB, rcB); LOADW(dnB, rcB);

        lds_barrier();  // E[par] of both streams published (the ONLY barrier)

        // ---- phase 2 ----
        // f = exp(uc - dc): pure input data -> overlaps the MFMAs
        float4 fF, fB;
        fF.x = __expf(ucF.x - dcF.x); fF.y = __expf(ucF.y - dcF.y);
        fF.z = __expf(ucF.z - dcF.z); fF.w = __expf(ucF.w - dcF.w);
        fB.x = __expf(ucB.x - dcB.x); fB.y = __expf(ucB.y - dcB.y);
        fB.z = __expf(ucB.z - dcB.z); fB.w = __expf(ucB.w - dcB.w);

        const unsigned short* ehpF = &EhF[par][0];
        const unsigned short* elpF = &ElF[par][0];
        const unsigned short* ehpB = &EhB[par][0];
        const unsigned short* elpB = &ElB[par][0];
        f32x4 aHHF = {0.f, 0.f, 0.f, 0.f}, aHLF = {0.f, 0.f, 0.f, 0.f},
              aLHF = {0.f, 0.f, 0.f, 0.f};
        f32x4 aHHB = {0.f, 0.f, 0.f, 0.f}, aHLB = {0.f, 0.f, 0.f, 0.f},
              aLHB = {0.f, 0.f, 0.f, 0.f};
        KC_STEP(F, 0); KC_STEP(B, 0);
        KC_STEP(F, 1); KC_STEP(B, 1);
        KC_STEP(F, 2); KC_STEP(B, 2);
        KC_STEP(F, 3); KC_STEP(B, 3);
        f32x4 accF = (aHHF + aHLF) + aLHF;
        f32x4 accB = (aHHB + aHLB) + aLHB;

        // E_next = acc * f: split hi/lo -> E[par^1] (readers one barrier away)
        unsigned short* ehnF = &EhF[par ^ 1][0];
        unsigned short* elnF = &ElF[par ^ 1][0];
        unsigned short* ehnB = &EhB[par ^ 1][0];
        unsigned short* elnB = &ElB[par ^ 1][0];
        EPUB(ehnF, elnF, 0, accF.x * fF.x);
        EPUB(ehnF, elnF, 1, accF.y * fF.y);
        EPUB(ehnF, elnF, 2, accF.z * fF.z);
        EPUB(ehnF, elnF, 3, accF.w * fF.w);
        EPUB(ehnB, elnB, 0, accB.x * fB.x);
        EPUB(ehnB, elnB, 1, accB.y * fB.y);
        EPUB(ehnB, elnB, 2, accB.z * fB.z);
        EPUB(ehnB, elnB, 3, accB.w * fB.w);

        // outputs (off the serial chain); per-row constant -W dropped
        float4 stF, stB;
        stF.x = __logf(accF.x) + ucF.x;
        stF.y = __logf(accF.y) + ucF.y;
        stF.z = __logf(accF.z) + ucF.z;
        stF.w = __logf(accF.w) + ucF.w;
        if (roF >= wloOff && roF < whiOff) STOREO(F, stF, roF);
        stB.x = __logf(accB.x);
        stB.y = __logf(accB.y);
        stB.z = __logf(accB.z);
        stB.w = __logf(accB.w);
        if (roB >= wloOff && roB < whiOff) STOREO(B, stB, roB);
    }

    // ---- fused combine tail: out = log_softmax(alpha + beta) for this
    // block's own window (rows wlo..whi-1, all 16 chains). All alpha/beta
    // values for these rows were stored by THIS block; __syncthreads drains
    // vmcnt (all stores complete) and barriers, reads hit the same L1/L2. ----
    __syncthreads();
    {
        const int hw = t >> 5;    // half-wave id 0..15
        const int li = t & 31;    // lane within half-wave
#pragma unroll
        for (int i = 0; i < (LCH * BB) / 16; ++i) {   // 16 iterations
            int idx = i * 16 + hw;                    // 0..255
            int bch = idx >> 4;                       // chain 0..15
            int r   = wlo + (idx & 15);               // window row
            float4*       o4 = (float4*)(alpha + ((size_t)bch * TT + r) * CC);
            const float4* b4 = (const float4*)(beta + ((size_t)bch * TT + r) * CC);
            float4 a = o4[li];
            float4 bv = b4[li];
            float4 z = float4{a.x + bv.x, a.y + bv.y, a.z + bv.z, a.w + bv.w};
            float m = fmaxf(fmaxf(z.x, z.y), fmaxf(z.z, z.w));
#pragma unroll
            for (int o = 1; o < 32; o <<= 1) m = fmaxf(m, __shfl_xor(m, o, 64));
            float sm = __expf(z.x - m) + __expf(z.y - m) +
                       __expf(z.z - m) + __expf(z.w - m);
#pragma unroll
            for (int o = 1; o < 32; o <<= 1) sm += __shfl_xor(sm, o, 64);
            float ls = m + __logf(sm);
            o4[li] = float4{z.x - ls, z.y - ls, z.z - ls, z.w - ls};
        }
    }
}

// ---------------------------------------------------------------------------
extern "C" void kernel_launch(void* const* d_in, const int* in_sizes, int n_in,
                              void* d_out, int out_size, void* d_ws, size_t ws_size,
                              hipStream_t stream) {
    const float* u_in = (const float*)d_in[0];   // (B, T, C) fp32
    const float* lt   = (const float*)d_in[1];   // (C, C)    fp32
    float*       out  = (float*)d_out;           // (B, T, C) fp32

    unsigned short* fr = (unsigned short*)d_ws;          // 131072 B of B-frags
    float* beta = (float*)d_ws + 2 * CC * CC;            // same offset as before

    prep_kernel<<<CC, CC, 0, stream>>>(lt, fr);
    scan_kernel<<<NCH, 512, 0, stream>>>(u_in, fr, out, beta);
}